// Round 4
// baseline (18.047 us; speedup 1.0000x reference)
//
#include <hip/hip_runtime.h>

// Polyphase resampler 16000 -> 14400 Hz (SpeedPerturb).
// stride 10, P = 9 phases, W = 14 taps.
// Thread owns period m: outputs t = 9m+j, j=0..8.
// out[t] = sum_w wav[10m - 6 + OFF[j] + w] * wgt[14 j + w],
// OFF = {0,1,2,3,4,5,6,8,9}.  Input staged to LDS coalesced
// (global_load_lds x16), window read back as 12x ds_read_b64
// (lane-stride 5 float2 units -> exactly the b64 bank floor, conflict-free).

#define RS_TPB 256
#define RS_N4 644   // float4 slots staged per block = 2576 floats >= 2574+off0

typedef __attribute__((address_space(1))) const void gvoid_t;
typedef __attribute__((address_space(3))) void lvoid_t;

__global__ __launch_bounds__(RS_TPB) void resample_kernel(
    const float* __restrict__ wav, const float* __restrict__ wgt,
    float* __restrict__ out, int N, int M, int TOT) {
  __shared__ __align__(16) float s_in[RS_N4 * 4];  // 10304 B, linear
  __shared__ float s_out[RS_TPB * 9];              // 9216 B

  const int b = blockIdx.y;
  const int m0 = blockIdx.x * RS_TPB;
  const int tid = threadIdx.x;
  const float* __restrict__ wrow = wav + (size_t)b * N;

  const int gstart = 10 * m0 - 6;
  const int off0 = gstart & 3;        // 0 or 2 (gstart is even)
  const int abase = gstart - off0;    // 16B-aligned float index of s_in[0]

  const bool interior = (abase >= 0) && (abase + RS_N4 * 4 <= N);
  if (interior) {
#pragma unroll
    for (int it = 0; it < 3; ++it) {
      const int i4 = it * RS_TPB + tid;
      if (i4 < RS_N4) {
        __builtin_amdgcn_global_load_lds(
            (gvoid_t*)(wrow + abase + (i4 << 2)),
            (lvoid_t*)&s_in[i4 << 2], 16, 0, 0);
      }
    }
  } else {
    for (int i = tid; i < RS_N4 * 4; i += RS_TPB) {
      const int gi = abase + i;
      s_in[i] = (gi >= 0 && gi < N) ? wrow[gi] : 0.0f;
    }
  }
  __syncthreads();

  const int m = m0 + tid;
  if (m < M) {
    float win[24];
    const float2* __restrict__ s2 = reinterpret_cast<const float2*>(s_in);
    const int d0 = 5 * tid + (off0 >> 1);   // window base in float2 units
#pragma unroll
    for (int r = 0; r < 12; ++r) {
      const float2 v = s2[d0 + r];
      win[2 * r] = v.x;
      win[2 * r + 1] = v.y;
    }
    const int OFF[9] = {0, 1, 2, 3, 4, 5, 6, 8, 9};
#pragma unroll
    for (int j = 0; j < 9; ++j) {
      float acc = 0.0f;
#pragma unroll
      for (int w = 0; w < 14; ++w)
        acc = fmaf(win[OFF[j] + w], wgt[14 * j + w], acc);
      s_out[tid * 9 + j] = acc;
    }
  }
  __syncthreads();

  // Coalesced float4 store of this block's contiguous output slab.
  int n_out = M - m0;
  if (n_out > RS_TPB) n_out = RS_TPB;
  n_out *= 9;                                  // 2304 or 1152: both %4 == 0
  const size_t obase = (size_t)b * TOT + (size_t)m0 * 9;
  float* __restrict__ orow = out + obase;
  const int n4 = n_out >> 2;
  for (int i4 = tid; i4 < n4; i4 += RS_TPB) {
    const float4 v = *reinterpret_cast<const float4*>(&s_out[i4 << 2]);
    *reinterpret_cast<float4*>(orow + (i4 << 2)) = v;
  }
}

extern "C" void kernel_launch(void* const* d_in, const int* in_sizes, int n_in,
                              void* d_out, int out_size, void* d_ws, size_t ws_size,
                              hipStream_t stream) {
  const float* wav = (const float*)d_in[0];
  const float* wgt = (const float*)d_in[1];
  float* out = (float*)d_out;

  const int N = 480000;
  const int B = in_sizes[0] / N;   // 16
  const int TOT = out_size / B;    // 432000
  const int M = (TOT + 8) / 9;     // 48000 periods

  dim3 grid((M + RS_TPB - 1) / RS_TPB, B);
  resample_kernel<<<grid, RS_TPB, 0, stream>>>(wav, wgt, out, N, M, TOT);
}

// Round 5
// 16.193 us; speedup vs baseline: 1.1145x; 1.1145x over previous
//
#include <hip/hip_runtime.h>

// Polyphase resampler 16000 -> 14400 Hz (SpeedPerturb).
// stride 10, P = 9 phases, W = 14 taps.
// Thread owns a PAIR of periods k -> outputs t = 18k+j, j=0..17.
// Window = wav[20k-8 .. 20k+27] (36 floats). 20k-8 is 16B-aligned ->
// 9 static float4 loads. Output index o_j = OFF[j%9] + 2 + 10*(j/9),
// OFF = {0,1,2,3,4,5,6,8,9}; max o+13 = 34 < 36. Zero-pad at row edges.

#define RS_TPB 256

__global__ __launch_bounds__(RS_TPB) void resample_kernel(
    const float* __restrict__ wav, const float* __restrict__ wgt,
    float* __restrict__ out, int N, int K, int TOT) {
  __shared__ float s_out[RS_TPB * 18];  // 18432 B

  const int b = blockIdx.y;
  const int k0 = blockIdx.x * RS_TPB;
  const int tid = threadIdx.x;
  const int k = k0 + tid;
  const float* __restrict__ wrow = wav + (size_t)b * N;

  if (k < K) {
    const int abase = 20 * k - 8;
    float win[36];
    if (abase >= 0 && abase + 36 <= N) {
#pragma unroll
      for (int r = 0; r < 9; ++r) {
        const float4 v = *reinterpret_cast<const float4*>(wrow + abase + (r << 2));
        win[4 * r + 0] = v.x;
        win[4 * r + 1] = v.y;
        win[4 * r + 2] = v.z;
        win[4 * r + 3] = v.w;
      }
    } else {
#pragma unroll
      for (int i = 0; i < 36; ++i) {
        const int gi = abase + i;
        win[i] = (gi >= 0 && gi < N) ? wrow[gi] : 0.0f;
      }
    }
    const int OFF[9] = {0, 1, 2, 3, 4, 5, 6, 8, 9};
#pragma unroll
    for (int j = 0; j < 18; ++j) {
      const int o = OFF[j % 9] + 2 + 10 * (j / 9);   // compile-time
      const float* wp = &wgt[14 * (j % 9)];
      float acc = 0.0f;
#pragma unroll
      for (int w = 0; w < 14; ++w) acc = fmaf(win[o + w], wp[w], acc);
      s_out[tid * 18 + j] = acc;   // stride-18 b32: 2-way per 32-lane phase = free
    }
  }
  __syncthreads();

  // Coalesced float4 store of the block's contiguous output slab.
  int nk = K - k0;
  if (nk > RS_TPB) nk = RS_TPB;
  const int n_out = nk * 18;                 // 4608 or 3456: both %4 == 0
  const size_t obase = (size_t)b * TOT + (size_t)k0 * 18;
  float* __restrict__ orow = out + obase;
  const int n4 = n_out >> 2;
  for (int i4 = tid; i4 < n4; i4 += RS_TPB) {
    const float4 v = *reinterpret_cast<const float4*>(&s_out[i4 << 2]);
    *reinterpret_cast<float4*>(orow + (i4 << 2)) = v;
  }
  for (int i = (n4 << 2) + tid; i < n_out; i += RS_TPB) orow[i] = s_out[i];
}

extern "C" void kernel_launch(void* const* d_in, const int* in_sizes, int n_in,
                              void* d_out, int out_size, void* d_ws, size_t ws_size,
                              hipStream_t stream) {
  const float* wav = (const float*)d_in[0];
  const float* wgt = (const float*)d_in[1];
  float* out = (float*)d_out;

  const int N = 480000;
  const int B = in_sizes[0] / N;   // 16
  const int TOT = out_size / B;    // 432000
  const int K = (TOT + 17) / 18;   // 24000 period-pairs

  dim3 grid((K + RS_TPB - 1) / RS_TPB, B);
  resample_kernel<<<grid, RS_TPB, 0, stream>>>(wav, wgt, out, N, K, TOT);
}